// Round 1
// baseline (693.676 us; speedup 1.0000x reference)
//
#include <hip/hip_runtime.h>
#include <stdint.h>

#define MODEL 1024
#define INNER 4096
#define NHEADS 16
#define HDIM 64
#define BATCH 4
#define SEQ 2048
#define MROWS (BATCH*SEQ)

typedef __bf16 bf16x8 __attribute__((ext_vector_type(8)));
typedef float f32x4 __attribute__((ext_vector_type(4)));
typedef unsigned short ushort8 __attribute__((ext_vector_type(8)));
typedef unsigned short ushort4v __attribute__((ext_vector_type(4)));

__device__ __forceinline__ unsigned short f2bf(float f) {
  unsigned u = __builtin_bit_cast(unsigned, f);
  u += 0x7FFFu + ((u >> 16) & 1u);
  return (unsigned short)(u >> 16);
}

#define AS1 __attribute__((address_space(1)))
#define AS3 __attribute__((address_space(3)))
__device__ __forceinline__ void gload_lds16(const void* g, void* l) {
  __builtin_amdgcn_global_load_lds((const AS1 void*)g, (AS3 void*)l, 16, 0, 0);
}

// ---------------- fp32 -> bf16 convert (vectorized) ----------------
__global__ __launch_bounds__(256) void k_cvt(const float* __restrict__ in,
                                             unsigned short* __restrict__ out, int n4) {
  int i = blockIdx.x * 256 + threadIdx.x;
  if (i < n4) {
    float4 v = ((const float4*)in)[i];
    ushort4v o = { f2bf(v.x), f2bf(v.y), f2bf(v.z), f2bf(v.w) };
    ((ushort4v*)out)[i] = o;
  }
}

// ---------------- W [K][N] fp32 -> Wt [N][K] bf16 ----------------
__global__ __launch_bounds__(256) void k_transpose(const float* __restrict__ W,
                                                   unsigned short* __restrict__ Wt,
                                                   int K, int N) {
  __shared__ float tile[32][33];
  const int n0 = blockIdx.x * 32, k0 = blockIdx.y * 32;
  const int c = threadIdx.x & 31, r4 = threadIdx.x >> 5; // r4 in 0..7
#pragma unroll
  for (int i = 0; i < 4; i++) {
    int r = r4 + i * 8;
    tile[r][c] = W[(size_t)(k0 + r) * N + n0 + c];
  }
  __syncthreads();
#pragma unroll
  for (int i = 0; i < 4; i++) {
    int r = r4 + i * 8;
    Wt[(size_t)(n0 + r) * K + k0 + c] = f2bf(tile[c][r]);
  }
}

// ---------------- GEMM: C[M][N] = A[M][K] * Bt[N][K]^T + bias ----------------
// OUTMODE: 0 = fp32, 1 = bf16, 2 = bf16 + relu
template <int OUTMODE>
__global__ __launch_bounds__(256) void k_gemm(const unsigned short* __restrict__ A,
                                              const unsigned short* __restrict__ Bt,
                                              const float* __restrict__ bias,
                                              void* __restrict__ Cout,
                                              int M, int N, int K) {
  __shared__ unsigned short As[128 * 32];
  __shared__ unsigned short Bs[128 * 32];
  const int t = threadIdx.x;
  const int lane = t & 63;
  const int w = t >> 6;
  const int li = lane & 15, lg = lane >> 4;
  const int bm = blockIdx.y * 128, bn = blockIdx.x * 128;
  const int wm = (w >> 1) * 64, wn = (w & 1) * 64;
  const int sr = t >> 2;          // staging row 0..63
  const int sc = (t & 3) * 8;     // staging col (8 bf16 = 16B)
  f32x4 acc[4][4] = {};
  const unsigned short* Abase = A + (size_t)(bm + sr) * K + sc;
  const unsigned short* Bbase = Bt + (size_t)(bn + sr) * K + sc;
  for (int k0 = 0; k0 < K; k0 += 32) {
    gload_lds16(Abase + k0, &As[w * 512]);
    gload_lds16(Abase + (size_t)64 * K + k0, &As[2048 + w * 512]);
    gload_lds16(Bbase + k0, &Bs[w * 512]);
    gload_lds16(Bbase + (size_t)64 * K + k0, &Bs[2048 + w * 512]);
    __syncthreads();
    bf16x8 a[4], b[4];
#pragma unroll
    for (int m = 0; m < 4; m++)
      a[m] = *(const bf16x8*)&As[(wm + m * 16 + li) * 32 + lg * 8];
#pragma unroll
    for (int n = 0; n < 4; n++)
      b[n] = *(const bf16x8*)&Bs[(wn + n * 16 + li) * 32 + lg * 8];
#pragma unroll
    for (int m = 0; m < 4; m++)
#pragma unroll
      for (int n = 0; n < 4; n++)
        acc[m][n] = __builtin_amdgcn_mfma_f32_16x16x32_bf16(a[m], b[n], acc[m][n], 0, 0, 0);
    __syncthreads();
  }
#pragma unroll
  for (int m = 0; m < 4; m++) {
    const int row = bm + wm + m * 16 + lg * 4;
#pragma unroll
    for (int n = 0; n < 4; n++) {
      const int col = bn + wn + n * 16 + li;
      const float bv = bias[col];
#pragma unroll
      for (int j = 0; j < 4; j++) {
        float v = acc[m][n][j] + bv;
        if (OUTMODE == 2) v = fmaxf(v, 0.f);
        if (OUTMODE == 0)
          ((float*)Cout)[(size_t)(row + j) * N + col] = v;
        else
          ((unsigned short*)Cout)[(size_t)(row + j) * N + col] = f2bf(v);
      }
    }
  }
}

// ---------------- flash attention ----------------
// q,k,v: bf16 [B][S][H*64] ; ctx out: bf16 [B][S][H*64]
__global__ __launch_bounds__(256) void k_attn(const unsigned short* __restrict__ q,
                                              const unsigned short* __restrict__ k,
                                              const unsigned short* __restrict__ v,
                                              const int* __restrict__ mask,
                                              unsigned short* __restrict__ ctx) {
  __shared__ unsigned short Ks[128 * 64];
  __shared__ unsigned short Vt[64 * 128];
  __shared__ unsigned short Ps[4][32 * 128];
  const int t = threadIdx.x, lane = t & 63, w = t >> 6;
  const int li = lane & 15, lg = lane >> 4;
  const int bh = blockIdx.y, b = bh >> 4, h = bh & 15;
  const int q0 = blockIdx.x * 128;
  const size_t basebs = (size_t)b * SEQ;

  bf16x8 qf[2][2];
#pragma unroll
  for (int m = 0; m < 2; m++)
#pragma unroll
    for (int kk = 0; kk < 2; kk++) {
      int row = q0 + w * 32 + m * 16 + li;
      qf[m][kk] = *(const bf16x8*)&q[(basebs + row) * MODEL + h * 64 + kk * 32 + lg * 8];
    }

  f32x4 acc_o[2][4] = {};
  float mrow[2][4], lrow[2][4];
#pragma unroll
  for (int m = 0; m < 2; m++)
#pragma unroll
    for (int j = 0; j < 4; j++) { mrow[m][j] = -3e38f; lrow[m][j] = 0.f; }

  const int sr = t >> 3;          // 0..31
  const int sc = (t & 7) * 8;     // 0..56

  for (int kt = 0; kt < SEQ; kt += 128) {
    // stage K tile [128][64] linear via global_load_lds
#pragma unroll
    for (int i = 0; i < 4; i++) {
      const unsigned short* g = k + (basebs + kt + sr + 32 * i) * MODEL + h * 64 + sc;
      gload_lds16(g, &Ks[w * 512 + i * 2048]);
    }
    // stage V transposed: Vt[d][kv]
#pragma unroll
    for (int i = 0; i < 4; i++) {
      ushort8 vv = *(const ushort8*)&v[(basebs + kt + sr + 32 * i) * MODEL + h * 64 + sc];
#pragma unroll
      for (int jj = 0; jj < 8; jj++)
        Vt[(sc + jj) * 128 + sr + 32 * i] = vv[jj];
    }
    __syncthreads();

    int mk[8];
#pragma unroll
    for (int n = 0; n < 8; n++) mk[n] = mask[b * SEQ + kt + n * 16 + li];

    // S = Q K^T
    f32x4 sacc[2][8] = {};
#pragma unroll
    for (int n = 0; n < 8; n++) {
      bf16x8 kf0 = *(const bf16x8*)&Ks[(n * 16 + li) * 64 + lg * 8];
      bf16x8 kf1 = *(const bf16x8*)&Ks[(n * 16 + li) * 64 + 32 + lg * 8];
#pragma unroll
      for (int m = 0; m < 2; m++) {
        sacc[m][n] = __builtin_amdgcn_mfma_f32_16x16x32_bf16(qf[m][0], kf0, sacc[m][n], 0, 0, 0);
        sacc[m][n] = __builtin_amdgcn_mfma_f32_16x16x32_bf16(qf[m][1], kf1, sacc[m][n], 0, 0, 0);
      }
    }

    // online softmax (rows live in lanes sharing lg; cols across li)
#pragma unroll
    for (int m = 0; m < 2; m++) {
#pragma unroll
      for (int j = 0; j < 4; j++) {
        float rmax = -3e38f;
#pragma unroll
        for (int n = 0; n < 8; n++) {
          float sv = sacc[m][n][j] * 0.125f;
          sv = (mk[n] == 0) ? -1e10f : sv;
          sacc[m][n][j] = sv;
          rmax = fmaxf(rmax, sv);
        }
        rmax = fmaxf(rmax, __shfl_xor(rmax, 1));
        rmax = fmaxf(rmax, __shfl_xor(rmax, 2));
        rmax = fmaxf(rmax, __shfl_xor(rmax, 4));
        rmax = fmaxf(rmax, __shfl_xor(rmax, 8));
        float mnew = fmaxf(mrow[m][j], rmax);
        float alpha = __expf(mrow[m][j] - mnew);
        mrow[m][j] = mnew;
        float rsum = 0.f;
#pragma unroll
        for (int n = 0; n < 8; n++) {
          float p = __expf(sacc[m][n][j] - mnew);
          sacc[m][n][j] = p;
          rsum += p;
        }
        rsum += __shfl_xor(rsum, 1);
        rsum += __shfl_xor(rsum, 2);
        rsum += __shfl_xor(rsum, 4);
        rsum += __shfl_xor(rsum, 8);
        lrow[m][j] = lrow[m][j] * alpha + rsum;
#pragma unroll
        for (int nd = 0; nd < 4; nd++) acc_o[m][nd][j] *= alpha;
      }
    }

    // P -> LDS (per-wave buffer)
#pragma unroll
    for (int m = 0; m < 2; m++)
#pragma unroll
      for (int n = 0; n < 8; n++)
#pragma unroll
        for (int j = 0; j < 4; j++)
          Ps[w][(m * 16 + lg * 4 + j) * 128 + n * 16 + li] = f2bf(sacc[m][n][j]);
    asm volatile("s_waitcnt lgkmcnt(0)" ::: "memory");

    // O += P V
#pragma unroll
    for (int kk = 0; kk < 4; kk++) {
      bf16x8 pa[2];
#pragma unroll
      for (int m = 0; m < 2; m++)
        pa[m] = *(const bf16x8*)&Ps[w][(m * 16 + li) * 128 + kk * 32 + lg * 8];
#pragma unroll
      for (int nd = 0; nd < 4; nd++) {
        bf16x8 vf = *(const bf16x8*)&Vt[(nd * 16 + li) * 128 + kk * 32 + lg * 8];
#pragma unroll
        for (int m = 0; m < 2; m++)
          acc_o[m][nd] = __builtin_amdgcn_mfma_f32_16x16x32_bf16(pa[m], vf, acc_o[m][nd], 0, 0, 0);
      }
    }
    __syncthreads();
  }

#pragma unroll
  for (int m = 0; m < 2; m++)
#pragma unroll
    for (int nd = 0; nd < 4; nd++)
#pragma unroll
      for (int j = 0; j < 4; j++) {
        int row = q0 + w * 32 + m * 16 + lg * 4 + j;
        int col = h * 64 + nd * 16 + li;
        float ov = acc_o[m][nd][j] / lrow[m][j];
        ctx[(basebs + row) * MODEL + col] = f2bf(ov);
      }
}

// ---------------- residual + LayerNorm ----------------
template <bool WB>
__global__ __launch_bounds__(256) void k_ln(const float* __restrict__ a,
                                            const float* __restrict__ bsrc,
                                            const float* __restrict__ gamma,
                                            const float* __restrict__ beta,
                                            float* __restrict__ outf,
                                            unsigned short* __restrict__ outb) {
  const int row = blockIdx.x;
  const int t = threadIdx.x;
  const size_t off = (size_t)row * MODEL + t * 4;
  float4 xa = *(const float4*)&a[off];
  float4 xb = *(const float4*)&bsrc[off];
  float z0 = xa.x + xb.x, z1 = xa.y + xb.y, z2 = xa.z + xb.z, z3 = xa.w + xb.w;
  float s = z0 + z1 + z2 + z3;
  float ss = z0 * z0 + z1 * z1 + z2 * z2 + z3 * z3;
#pragma unroll
  for (int o = 1; o < 64; o <<= 1) { s += __shfl_xor(s, o); ss += __shfl_xor(ss, o); }
  __shared__ float red[8];
  const int lane = t & 63, w = t >> 6;
  if (lane == 0) { red[w] = s; red[4 + w] = ss; }
  __syncthreads();
  s = red[0] + red[1] + red[2] + red[3];
  ss = red[4] + red[5] + red[6] + red[7];
  float mu = s * (1.f / MODEL);
  float var = ss * (1.f / MODEL) - mu * mu;
  float inv = rsqrtf(var + 1e-5f);
  float4 g = *(const float4*)&gamma[t * 4];
  float4 be = *(const float4*)&beta[t * 4];
  float o0 = (z0 - mu) * inv * g.x + be.x;
  float o1 = (z1 - mu) * inv * g.y + be.y;
  float o2 = (z2 - mu) * inv * g.z + be.z;
  float o3 = (z3 - mu) * inv * g.w + be.w;
  float4 ov = {o0, o1, o2, o3};
  *(float4*)&outf[off] = ov;
  if (WB) {
    ushort4v ob = {f2bf(o0), f2bf(o1), f2bf(o2), f2bf(o3)};
    *(ushort4v*)&outb[off] = ob;
  }
}

extern "C" void kernel_launch(void* const* d_in, const int* in_sizes, int n_in,
                              void* d_out, int out_size, void* d_ws, size_t ws_size,
                              hipStream_t stream) {
  (void)in_sizes; (void)n_in; (void)out_size; (void)ws_size;
  const float* x   = (const float*)d_in[0];
  const int*   mask= (const int*)d_in[1];
  const float* Wq  = (const float*)d_in[2];
  const float* bq  = (const float*)d_in[3];
  const float* Wk  = (const float*)d_in[4];
  const float* bk  = (const float*)d_in[5];
  const float* Wv  = (const float*)d_in[6];
  const float* bv  = (const float*)d_in[7];
  const float* Wo  = (const float*)d_in[8];
  const float* bo  = (const float*)d_in[9];
  const float* g1  = (const float*)d_in[10];
  const float* be1 = (const float*)d_in[11];
  const float* W1  = (const float*)d_in[12];
  const float* b1  = (const float*)d_in[13];
  const float* W2  = (const float*)d_in[14];
  const float* b2  = (const float*)d_in[15];
  const float* g2  = (const float*)d_in[16];
  const float* be2 = (const float*)d_in[17];
  float* out = (float*)d_out;

  char* p = (char*)d_ws;
  auto alloc = [&](size_t bytes) { char* r = p; p += (bytes + 255) & ~(size_t)255; return r; };
  unsigned short* xb   = (unsigned short*)alloc((size_t)MROWS * MODEL * 2);
  unsigned short* WqT  = (unsigned short*)alloc((size_t)MODEL * MODEL * 2);
  unsigned short* WkT  = (unsigned short*)alloc((size_t)MODEL * MODEL * 2);
  unsigned short* WvT  = (unsigned short*)alloc((size_t)MODEL * MODEL * 2);
  unsigned short* WoT  = (unsigned short*)alloc((size_t)MODEL * MODEL * 2);
  unsigned short* W1T  = (unsigned short*)alloc((size_t)MODEL * INNER * 2);
  unsigned short* W2T  = (unsigned short*)alloc((size_t)INNER * MODEL * 2);
  unsigned short* qb   = (unsigned short*)alloc((size_t)MROWS * MODEL * 2);
  unsigned short* kb   = (unsigned short*)alloc((size_t)MROWS * MODEL * 2);
  unsigned short* vb   = (unsigned short*)alloc((size_t)MROWS * MODEL * 2);
  unsigned short* ctxb = (unsigned short*)alloc((size_t)MROWS * MODEL * 2);
  float* attn_out      = (float*)alloc((size_t)MROWS * MODEL * 4);
  float* y1f           = (float*)alloc((size_t)MROWS * MODEL * 4);
  unsigned short* y1b  = (unsigned short*)alloc((size_t)MROWS * MODEL * 2);
  // aliases over dead buffers:
  unsigned short* h1 = qb;        // [MROWS][INNER] bf16 = 64MB over qb..ctxb
  float* ff = attn_out;           // [MROWS][MODEL] fp32

  // convert & transpose
  k_cvt<<<(MROWS * MODEL / 4) / 256, 256, 0, stream>>>(x, xb, MROWS * MODEL / 4);
  k_transpose<<<dim3(MODEL / 32, MODEL / 32), 256, 0, stream>>>(Wq, WqT, MODEL, MODEL);
  k_transpose<<<dim3(MODEL / 32, MODEL / 32), 256, 0, stream>>>(Wk, WkT, MODEL, MODEL);
  k_transpose<<<dim3(MODEL / 32, MODEL / 32), 256, 0, stream>>>(Wv, WvT, MODEL, MODEL);
  k_transpose<<<dim3(MODEL / 32, MODEL / 32), 256, 0, stream>>>(Wo, WoT, MODEL, MODEL);
  k_transpose<<<dim3(INNER / 32, MODEL / 32), 256, 0, stream>>>(W1, W1T, MODEL, INNER);
  k_transpose<<<dim3(MODEL / 32, INNER / 32), 256, 0, stream>>>(W2, W2T, INNER, MODEL);

  // QKV projections
  k_gemm<1><<<dim3(MODEL / 128, MROWS / 128), 256, 0, stream>>>(xb, WqT, bq, qb, MROWS, MODEL, MODEL);
  k_gemm<1><<<dim3(MODEL / 128, MROWS / 128), 256, 0, stream>>>(xb, WkT, bk, kb, MROWS, MODEL, MODEL);
  k_gemm<1><<<dim3(MODEL / 128, MROWS / 128), 256, 0, stream>>>(xb, WvT, bv, vb, MROWS, MODEL, MODEL);

  // attention
  k_attn<<<dim3(SEQ / 128, BATCH * NHEADS), 256, 0, stream>>>(qb, kb, vb, mask, ctxb);

  // output projection (fp32 out for residual)
  k_gemm<0><<<dim3(MODEL / 128, MROWS / 128), 256, 0, stream>>>(ctxb, WoT, bo, attn_out, MROWS, MODEL, MODEL);

  // LN1: y1 = LN(x + attn_out)
  k_ln<true><<<MROWS, 256, 0, stream>>>(x, attn_out, g1, be1, y1f, y1b);

  // FF1: h1 = relu(y1 @ W1 + b1)
  k_gemm<2><<<dim3(INNER / 128, MROWS / 128), 256, 0, stream>>>(y1b, W1T, b1, h1, MROWS, INNER, MODEL);

  // FF2: ff = h1 @ W2 + b2
  k_gemm<0><<<dim3(MODEL / 128, MROWS / 128), 256, 0, stream>>>(h1, W2T, b2, ff, MROWS, MODEL, INNER);

  // LN2 -> out
  k_ln<false><<<MROWS, 256, 0, stream>>>(y1f, ff, g2, be2, out, nullptr);
}